// Round 5
// baseline (92.867 us; speedup 1.0000x reference)
//
#include <hip/hip_runtime.h>
#include <cfloat>

// Problem constants (match reference setup_inputs)
#define BB 4
#define NQ 8192
#define NK 2048
#define CC 128
#define C4 (CC / 4)            // 32 float4 per feature row

#define QPB 64                 // queries per block (= lane id)
#define SPLITS 16              // key splits, one wave each (wave-uniform)
#define KPS (NK / SPLITS)      // 128 keys per split (local idx fits 7 bits)
#define NTHR (QPB * SPLITS)    // 1024 threads per block

typedef float sfvec __attribute__((ext_vector_type(16)));   // 4 packed keys

// ---------------------------------------------------------------------------
// Kernel 1: pack keys as float4 {x, y, z, |k|^2} into workspace
// ---------------------------------------------------------------------------
__global__ __launch_bounds__(256) void pack_keys(
    const float* __restrict__ xyz_k, float4* __restrict__ keys)
{
    int i = blockIdx.x * 256 + threadIdx.x;   // flat b*NK + k
    if (i < BB * NK) {
        float x = xyz_k[i * 3 + 0];
        float y = xyz_k[i * 3 + 1];
        float z = xyz_k[i * 3 + 2];
        keys[i] = make_float4(x, y, z, fmaf(x, x, fmaf(y, y, z * z)));
    }
}

// ---------------------------------------------------------------------------
// Kernel 2: fused kNN + interpolation.
//   Scan reads keys on the SCALAR pipe (s_load_dwordx16, 4 keys/instr) —
//   round-3/4 A/B showed the scan is bound by per-key VMEM/LDS instruction
//   issue (~20.5 us of shared-pipe time), not VALU. Scalar keys leave only
//   ~10 VALU/key on the vector pipe.
//   grid = (NQ/QPB, BB), block = 1024 = 64 queries x 16 splits
// ---------------------------------------------------------------------------
__global__ __launch_bounds__(NTHR, 8) void fp_main(
    const float*  __restrict__ xyz_q,
    const float4* __restrict__ keys,
    const float4* __restrict__ vk,
    float4*       __restrict__ out)
{
    // packed fp64 candidates: (bits(dd) & ~0x7FF) | global_kidx  (11 bits)
    __shared__ unsigned long long rd[NTHR][4];   // 32 KiB
    __shared__ float sw[QPB][4];
    __shared__ int   si[QPB][4];

    const int b     = blockIdx.y;
    const int qbase = blockIdx.x * QPB;
    const int tid   = threadIdx.x;
    const int lane  = tid & 63;                  // query within block
    const int split = tid >> 6;                  // wave id == key split (uniform)
    const int q     = qbase + lane;

    const float qx = xyz_q[(b * NQ + q) * 3 + 0];
    const float qy = xyz_q[(b * NQ + q) * 3 + 1];
    const float qz = xyz_q[(b * NQ + q) * 3 + 2];
    // t = |q-k|^2 + 1e-3  (strictly positive; bias >> fp32 rounding error)
    const float qq = fmaf(qx, qx, fmaf(qy, qy, qz * qz)) + 1.0e-3f;
    const float ax = -2.0f * qx, ay = -2.0f * qy, az = -2.0f * qz;

    // wave-uniform key range
    const int kbeg = __builtin_amdgcn_readfirstlane(split * KPS);
    const sfvec* kp4 = (const sfvec*)(keys + (size_t)b * NK + kbeg);

    // ---- phase 1: scalar-pipe key fetch + branchless packed top-4 ----
    // invariant: u0 <= u1 <= u2 <= u3 (positive floats, low 7 bits = local idx)
    float u0 = FLT_MAX, u1 = FLT_MAX, u2 = FLT_MAX, u3 = FLT_MAX;

    #pragma unroll 1
    for (int jb = 0; jb < KPS / 4; ++jb) {       // 32 blocks of 4 keys
        const sfvec* addr = kp4 + jb;            // uniform address
        sfvec kk;
        asm("s_load_dwordx16 %0, %1, 0x0" : "=s"(kk) : "s"(addr));
        asm("s_waitcnt lgkmcnt(0)" : "+s"(kk));  // order: wait before use
        #pragma unroll
        for (int c = 0; c < 4; ++c) {
            float kx = kk[c * 4 + 0];            // SGPR operands
            float ky = kk[c * 4 + 1];
            float kz = kk[c * 4 + 2];
            float kw = kk[c * 4 + 3];
            float t = fmaf(ax, kx, fmaf(ay, ky, fmaf(az, kz, qq))) + kw;
            // keep 17 significant bits, low 7 = local key index (VOP2 literals)
            float p = __uint_as_float((__float_as_uint(t) & 0xFFFFFF80u)
                                      | (unsigned)(jb * 4 + c));
            // sorted insert, 4 ops (3x v_med3_f32 + v_min_f32)
            u3 = __builtin_amdgcn_fmed3f(p, u2, u3);
            u2 = __builtin_amdgcn_fmed3f(p, u1, u2);
            u1 = __builtin_amdgcn_fmed3f(p, u0, u1);
            u0 = fminf(u0, p);
        }
    }

    // ---- phase 2a: every thread fp64-refines its own 4 candidates ----
    {
        const float4* kg = keys + (size_t)b * NK;
        float uu[4] = { u0, u1, u2, u3 };
        #pragma unroll
        for (int c = 0; c < 4; ++c) {
            int kidx = kbeg + (int)(__float_as_uint(uu[c]) & 0x7Fu);
            float4 ka = kg[kidx];                // divergent gather, 4 per thread
            double dx = (double)qx - (double)ka.x;
            double dy = (double)qy - (double)ka.y;
            double dz = (double)qz - (double)ka.z;
            double dd = dx * dx + dy * dy + dz * dz;   // exact ordering for fp32 inputs
            unsigned long long pk =
                (((unsigned long long)__double_as_longlong(dd)) & ~0x7FFull)
                | (unsigned long long)kidx;
            rd[tid][c] = pk;
        }
    }
    __syncthreads();

    // ---- phase 2b: wave 0 selects exact top-3 of 64 candidates per query ----
    if (tid < QPB) {
        // packed uint64s reinterpreted as positive doubles stay order-correct
        double m0 = DBL_MAX, m1 = DBL_MAX, m2 = DBL_MAX;
        #pragma unroll 4
        for (int s = 0; s < SPLITS; ++s) {
            #pragma unroll
            for (int c = 0; c < 4; ++c) {
                double x = __longlong_as_double((long long)rd[s * QPB + lane][c]);
                double a1 = fmax(x, m1), a0 = fmax(x, m0);
                m2 = fmin(m2, a1);
                m1 = fmin(m1, a0);
                m0 = fmin(m0, x);
            }
        }
        unsigned long long b0 = (unsigned long long)__double_as_longlong(m0);
        unsigned long long b1 = (unsigned long long)__double_as_longlong(m1);
        unsigned long long b2 = (unsigned long long)__double_as_longlong(m2);
        double e0 = __longlong_as_double((long long)(b0 & ~0x7FFull));
        double e1 = __longlong_as_double((long long)(b1 & ~0x7FFull));
        double e2 = __longlong_as_double((long long)(b2 & ~0x7FFull));
        e0 = fmax(e0, 1e-10);
        e1 = fmax(e1, 1e-10);
        e2 = fmax(e2, 1e-10);
        double w0 = 1.0 / e0, w1 = 1.0 / e1, w2 = 1.0 / e2;
        double s  = w0 + w1 + w2;
        sw[lane][0] = (float)(w0 / s);
        sw[lane][1] = (float)(w1 / s);
        sw[lane][2] = (float)(w2 / s);
        si[lane][0] = (int)(b0 & 0x7FFull);
        si[lane][1] = (int)(b1 & 0x7FFull);
        si[lane][2] = (int)(b2 & 0x7FFull);
    }
    __syncthreads();

    // ---- phase 3: gather + weighted sum, coalesced float4 writes ----
    const float4* vb = vk + (size_t)b * NK * C4;
    float4* ob = out + ((size_t)b * NQ + qbase) * C4;
    #pragma unroll
    for (int r = 0; r < (QPB * C4) / NTHR; ++r) {   // 2 iters
        int o  = r * NTHR + tid;
        int qq2 = o >> 5;         // C4 = 32 float4 per query
        int c4 = o & (C4 - 1);
        float w0 = sw[qq2][0], w1 = sw[qq2][1], w2 = sw[qq2][2];
        int   j0 = si[qq2][0], j1 = si[qq2][1], j2 = si[qq2][2];
        float4 v0 = vb[j0 * C4 + c4];
        float4 v1 = vb[j1 * C4 + c4];
        float4 v2 = vb[j2 * C4 + c4];
        float4 res;
        res.x = fmaf(w0, v0.x, fmaf(w1, v1.x, w2 * v2.x));
        res.y = fmaf(w0, v0.y, fmaf(w1, v1.y, w2 * v2.y));
        res.z = fmaf(w0, v0.z, fmaf(w1, v1.z, w2 * v2.z));
        res.w = fmaf(w0, v0.w, fmaf(w1, v1.w, w2 * v2.w));
        ob[o] = res;
    }
}

// ---------------------------------------------------------------------------
extern "C" void kernel_launch(void* const* d_in, const int* in_sizes, int n_in,
                              void* d_out, int out_size, void* d_ws, size_t ws_size,
                              hipStream_t stream)
{
    const float* xyz_q = (const float*)d_in[0];
    const float* xyz_k = (const float*)d_in[1];
    const float* v_k   = (const float*)d_in[2];

    float4* keys = (float4*)d_ws;   // BB*NK float4 = 128 KiB scratch

    pack_keys<<<dim3((BB * NK + 255) / 256), dim3(256), 0, stream>>>(xyz_k, keys);
    fp_main<<<dim3(NQ / QPB, BB), dim3(NTHR), 0, stream>>>(
        xyz_q, keys, (const float4*)v_k, (float4*)d_out);
}

// Round 6
// 90.230 us; speedup vs baseline: 1.0292x; 1.0292x over previous
//
#include <hip/hip_runtime.h>
#include <cfloat>

// Problem constants (match reference setup_inputs)
#define BB 4
#define NQ 8192
#define NK 2048
#define CC 128
#define C4 (CC / 4)            // 32 float4 per feature row

#define QPB 64                 // queries per block
#define SPLITS 16              // key splits
#define KPS (NK / SPLITS)      // 128 keys per split
#define QPT 4                  // queries per thread (amortize each key read 4x)
#define NTHR (QPB * SPLITS / QPT)   // 256 threads
#define RD_ROW 68              // 64 u32 + 4 pad (bank-conflict break)

static __device__ __forceinline__ float fmed3(float a, float b, float c) {
    return __builtin_amdgcn_fmed3f(a, b, c);
}

// ---------------------------------------------------------------------------
// Kernel 1: pack keys as float4 {x, y, z, |k|^2} into workspace
// ---------------------------------------------------------------------------
__global__ __launch_bounds__(256) void pack_keys(
    const float* __restrict__ xyz_k, float4* __restrict__ keys)
{
    int i = blockIdx.x * 256 + threadIdx.x;   // flat b*NK + k
    if (i < BB * NK) {
        float x = xyz_k[i * 3 + 0];
        float y = xyz_k[i * 3 + 1];
        float z = xyz_k[i * 3 + 2];
        keys[i] = make_float4(x, y, z, fmaf(x, x, fmaf(y, y, z * z)));
    }
}

// ---------------------------------------------------------------------------
// Kernel 2: fused kNN + interpolation, 4 queries/thread.
//   R3/R4/R5 A/B pinned the scan as LDS/VMEM *instruction-issue* bound
//   (12 cyc per ds_read_b128 x waves x keys). qpt=4 cuts key-read instrs 4x;
//   scan becomes VALU-bound (~8 us/CU model).
//   grid = (NQ/QPB, BB) = 512 blocks (2/CU), block = 256 = 64q x 16 splits / 4
// ---------------------------------------------------------------------------
__global__ __launch_bounds__(NTHR, 2) void fp_main(
    const float*  __restrict__ xyz_q,
    const float4* __restrict__ keys,
    const float4* __restrict__ vk,
    float4*       __restrict__ out)
{
    __shared__ float4  ks[NK];              // 32 KiB: {x,y,z,|k|^2}
    __shared__ unsigned rd[QPB][RD_ROW];    // 17 KiB: packed (dist|global idx)
    __shared__ float   sw[QPB][4];
    __shared__ int     si[QPB][4];

    const int b     = blockIdx.y;
    const int qbase = blockIdx.x * QPB;
    const int tid   = threadIdx.x;
    const int split = tid >> 4;             // 16 threads per split
    const int g     = tid & 15;             // query group: handles g, g+16, g+32, g+48

    // ---- stage packed keys into LDS (coalesced b128, 8 per thread) ----
    #pragma unroll
    for (int i = tid; i < NK; i += NTHR) ks[i] = keys[(size_t)b * NK + i];

    // ---- load 4 queries, precompute rank coefficients ----
    float ax[QPT], ay[QPT], az[QPT], qb_[QPT];
    #pragma unroll
    for (int qi = 0; qi < QPT; ++qi) {
        int q = qbase + g + 16 * qi;
        float qx = xyz_q[(b * NQ + q) * 3 + 0];
        float qy = xyz_q[(b * NQ + q) * 3 + 1];
        float qz = xyz_q[(b * NQ + q) * 3 + 2];
        ax[qi] = -2.0f * qx; ay[qi] = -2.0f * qy; az[qi] = -2.0f * qz;
        // t = |q-k|^2 + 1e-3: strictly positive (packed-float order trick valid)
        qb_[qi] = fmaf(qx, qx, fmaf(qy, qy, qz * qz)) + 1.0e-3f;
    }
    __syncthreads();

    const int kbeg = split * KPS;

    // ---- phase 1: scan 128 keys x 4 queries, branchless packed top-4 ----
    // pack = (dist bits & 0xFFFFF800) | global_kidx (11 bits, 13-bit quant —
    // co-quantum-quadruple probability ~1e-15/query: safe)
    float u[QPT][4];
    #pragma unroll
    for (int qi = 0; qi < QPT; ++qi)
        u[qi][0] = u[qi][1] = u[qi][2] = u[qi][3] = FLT_MAX;

    #pragma unroll 8
    for (int j = 0; j < KPS; ++j) {
        float4 kk = ks[kbeg + j];           // 1 read serves 4 query-pairs
        unsigned kidx = (unsigned)(kbeg + j);
        #pragma unroll
        for (int qi = 0; qi < QPT; ++qi) {
            float t = fmaf(ax[qi], kk.x,
                      fmaf(ay[qi], kk.y,
                      fmaf(az[qi], kk.z, qb_[qi]))) + kk.w;
            float p = __uint_as_float((__float_as_uint(t) & 0xFFFFF800u) | kidx);
            u[qi][3] = fmed3(p, u[qi][2], u[qi][3]);
            u[qi][2] = fmed3(p, u[qi][1], u[qi][2]);
            u[qi][1] = fmed3(p, u[qi][0], u[qi][1]);
            u[qi][0] = fminf(u[qi][0], p);
        }
    }

    // ---- write per-(query,split) top-4 as one uint4 each ----
    #pragma unroll
    for (int qi = 0; qi < QPT; ++qi) {
        int ql = g + 16 * qi;
        uint4 v = make_uint4(__float_as_uint(u[qi][0]), __float_as_uint(u[qi][1]),
                             __float_as_uint(u[qi][2]), __float_as_uint(u[qi][3]));
        *(uint4*)&rd[ql][split * 4] = v;    // 16B-aligned (row 272B)
    }
    __syncthreads();

    // ---- phase 2: one wave merges 64 candidates -> top-8 -> fp64 refine ----
    if (tid < QPB) {
        const int ql = tid;
        float m[8];
        #pragma unroll
        for (int c = 0; c < 8; ++c) m[c] = FLT_MAX;
        #pragma unroll 4
        for (int i = 0; i < SPLITS; ++i) {
            uint4 v = *(const uint4*)&rd[ql][i * 4];
            unsigned vv[4] = { v.x, v.y, v.z, v.w };
            #pragma unroll
            for (int c = 0; c < 4; ++c) {
                float p = __uint_as_float(vv[c]);
                m[7] = fmed3(p, m[6], m[7]);
                m[6] = fmed3(p, m[5], m[6]);
                m[5] = fmed3(p, m[4], m[5]);
                m[4] = fmed3(p, m[3], m[4]);
                m[3] = fmed3(p, m[2], m[3]);
                m[2] = fmed3(p, m[1], m[2]);
                m[1] = fmed3(p, m[0], m[1]);
                m[0] = fminf(m[0], p);
            }
        }
        // exact fp64 refine of the 8 survivors (diff form: exact for fp32 in)
        int q = qbase + ql;
        double qx = (double)xyz_q[(b * NQ + q) * 3 + 0];
        double qy = (double)xyz_q[(b * NQ + q) * 3 + 1];
        double qz = (double)xyz_q[(b * NQ + q) * 3 + 2];
        double M0 = DBL_MAX, M1 = DBL_MAX, M2 = DBL_MAX;
        #pragma unroll
        for (int c = 0; c < 8; ++c) {
            unsigned ki = __float_as_uint(m[c]) & 0x7FFu;
            float4 ka = ks[ki];
            double dx = qx - (double)ka.x;
            double dy = qy - (double)ka.y;
            double dz = qz - (double)ka.z;
            double dd = dx * dx + dy * dy + dz * dz;
            double x = __longlong_as_double(
                (long long)((((unsigned long long)__double_as_longlong(dd)) & ~0x7FFull)
                            | (unsigned long long)ki));
            double a1 = fmax(x, M1), a0 = fmax(x, M0);
            M2 = fmin(M2, a1);
            M1 = fmin(M1, a0);
            M0 = fmin(M0, x);
        }
        unsigned long long b0 = (unsigned long long)__double_as_longlong(M0);
        unsigned long long b1 = (unsigned long long)__double_as_longlong(M1);
        unsigned long long b2 = (unsigned long long)__double_as_longlong(M2);
        double e0 = __longlong_as_double((long long)(b0 & ~0x7FFull));
        double e1 = __longlong_as_double((long long)(b1 & ~0x7FFull));
        double e2 = __longlong_as_double((long long)(b2 & ~0x7FFull));
        e0 = fmax(e0, 1e-10);
        e1 = fmax(e1, 1e-10);
        e2 = fmax(e2, 1e-10);
        double w0 = 1.0 / e0, w1 = 1.0 / e1, w2 = 1.0 / e2;
        double s  = w0 + w1 + w2;
        sw[ql][0] = (float)(w0 / s);
        sw[ql][1] = (float)(w1 / s);
        sw[ql][2] = (float)(w2 / s);
        si[ql][0] = (int)(b0 & 0x7FFull);
        si[ql][1] = (int)(b1 & 0x7FFull);
        si[ql][2] = (int)(b2 & 0x7FFull);
    }
    __syncthreads();

    // ---- phase 3: gather + weighted sum, coalesced float4 writes ----
    const float4* vb = vk + (size_t)b * NK * C4;
    float4* ob = out + ((size_t)b * NQ + qbase) * C4;
    #pragma unroll
    for (int r = 0; r < (QPB * C4) / NTHR; ++r) {   // 8 iters
        int o  = r * NTHR + tid;
        int qq = o >> 5;          // C4 = 32 float4 per query
        int c4 = o & (C4 - 1);
        float w0 = sw[qq][0], w1 = sw[qq][1], w2 = sw[qq][2];
        int   j0 = si[qq][0], j1 = si[qq][1], j2 = si[qq][2];
        float4 v0 = vb[j0 * C4 + c4];
        float4 v1 = vb[j1 * C4 + c4];
        float4 v2 = vb[j2 * C4 + c4];
        float4 res;
        res.x = fmaf(w0, v0.x, fmaf(w1, v1.x, w2 * v2.x));
        res.y = fmaf(w0, v0.y, fmaf(w1, v1.y, w2 * v2.y));
        res.z = fmaf(w0, v0.z, fmaf(w1, v1.z, w2 * v2.z));
        res.w = fmaf(w0, v0.w, fmaf(w1, v1.w, w2 * v2.w));
        ob[o] = res;
    }
}

// ---------------------------------------------------------------------------
extern "C" void kernel_launch(void* const* d_in, const int* in_sizes, int n_in,
                              void* d_out, int out_size, void* d_ws, size_t ws_size,
                              hipStream_t stream)
{
    const float* xyz_q = (const float*)d_in[0];
    const float* xyz_k = (const float*)d_in[1];
    const float* v_k   = (const float*)d_in[2];

    float4* keys = (float4*)d_ws;   // BB*NK float4 = 128 KiB scratch

    pack_keys<<<dim3((BB * NK + 255) / 256), dim3(256), 0, stream>>>(xyz_k, keys);
    fp_main<<<dim3(NQ / QPB, BB), dim3(NTHR), 0, stream>>>(
        xyz_q, keys, (const float4*)v_k, (float4*)d_out);
}